// Round 4
// baseline (231.931 us; speedup 1.0000x reference)
//
#include <hip/hip_runtime.h>
#include <math.h>

// Problem constants
#define HH 2048
#define EE 64
#define TOPK 8
#define NT 16384
#define MT 32            // tokens per WG
#define KC 16            // K elems per chunk
#define KQR 512          // K range per K-quarter (in-WG K-split 4 across waves)
#define NCH 32           // KQR / KC
#define LS 68            // slog row stride (floats)

typedef __attribute__((ext_vector_type(8)))  short short8;  // 8 bf16 (4 VGPRs)
typedef __attribute__((ext_vector_type(16))) float f32x16;  // 32x32 MFMA acc

// 3-limb bf16 split: v = h + m + l + eps, |eps| <= 2^-25 |v|.
// h,m by truncation (residual exactly representable), l by RNE.
// (identical to the round-3 harness-passing version)
static __device__ __forceinline__ void cvt3(const float4& a, const float4& b,
                                            short8& h, short8& m, short8& l)
{
    const float v[8] = {a.x, a.y, a.z, a.w, b.x, b.y, b.z, b.w};
#pragma unroll
    for (int i = 0; i < 8; ++i) {
        const unsigned int u = __float_as_uint(v[i]);
        h[i] = (short)(u >> 16);
        const float r1 = v[i] - __uint_as_float(u & 0xffff0000u);
        const unsigned int u1 = __float_as_uint(r1);
        m[i] = (short)(u1 >> 16);
        const float r2 = r1 - __uint_as_float(u1 & 0xffff0000u);
        const unsigned int u2 = __float_as_uint(r2);
        l[i] = (short)((u2 + 0x7fffu + ((u2 >> 16) & 1u)) >> 16);
    }
}

// Fused router, barrier-free main loop. 256 threads = 4 waves = 4 K-quarters
// over the same 32 tokens. W fragments loaded straight from global (L2-resident
// 512 KB) into registers; x streamed once from HBM. 4-deep register pipeline.
__global__ __launch_bounds__(256, 2) void router_fused(
    const float* __restrict__ x,          // [NT, H] fp32
    const float* __restrict__ w,          // [E, H]  fp32
    float* __restrict__ out_logits,
    float* __restrict__ out_wts,
    float* __restrict__ out_idx)
{
    __shared__ float slog[MT * LS];       // 8.7 KB; only used in epilogue

    const int t    = threadIdx.x;
    const int wv   = t >> 6;
    const int lane = t & 63;
    const int kq   = wv;                  // K-quarter 0..3
    const int l5   = lane >> 5;           // k-octet within 16-k chunk
    const int lr   = lane & 31;           // token row (A) / expert col (B)
    const int tok0 = blockIdx.x * MT;

    // A source: lane lr = token, 32B contiguous per lane (octet l5).
    const float* xp  = x + (size_t)(tok0 + lr) * HH + kq * KQR + l5 * 8;
    // B sources: lane lr = expert col within eb-block; same 32B/lane shape.
    const float* wp0 = w + (size_t)(lr)      * HH + kq * KQR + l5 * 8;
    const float* wp1 = w + (size_t)(32 + lr) * HH + kq * KQR + l5 * 8;

    f32x16 accM0 = {0}, accM1 = {0};   // hh terms (eb 0/1)
    f32x16 accS0 = {0}, accS1 = {0};   // small terms: hm+mh+hl+lh+mm

    struct Chunk { float4 x0, x1, a0, a1, b0, b1; };
    Chunk S0, S1, S2, S3;

    auto load = [&](Chunk& s, int c) {
        const int o = c * KC;
        s.x0 = *(const float4*)(xp  + o);
        s.x1 = *(const float4*)(xp  + o + 4);
        s.a0 = *(const float4*)(wp0 + o);
        s.a1 = *(const float4*)(wp0 + o + 4);
        s.b0 = *(const float4*)(wp1 + o);
        s.b1 = *(const float4*)(wp1 + o + 4);
    };

    auto compute = [&](const Chunk& s) {
        short8 xh, xm, xl;
        cvt3(s.x0, s.x1, xh, xm, xl);
        {   // eb = 0
            short8 bh, bm, bl;
            cvt3(s.a0, s.a1, bh, bm, bl);
            accM0 = __builtin_amdgcn_mfma_f32_32x32x16_bf16(xh, bh, accM0, 0, 0, 0);
            accS0 = __builtin_amdgcn_mfma_f32_32x32x16_bf16(xh, bm, accS0, 0, 0, 0);
            accS0 = __builtin_amdgcn_mfma_f32_32x32x16_bf16(xm, bh, accS0, 0, 0, 0);
            accS0 = __builtin_amdgcn_mfma_f32_32x32x16_bf16(xh, bl, accS0, 0, 0, 0);
            accS0 = __builtin_amdgcn_mfma_f32_32x32x16_bf16(xl, bh, accS0, 0, 0, 0);
            accS0 = __builtin_amdgcn_mfma_f32_32x32x16_bf16(xm, bm, accS0, 0, 0, 0);
        }
        {   // eb = 1
            short8 bh, bm, bl;
            cvt3(s.b0, s.b1, bh, bm, bl);
            accM1 = __builtin_amdgcn_mfma_f32_32x32x16_bf16(xh, bh, accM1, 0, 0, 0);
            accS1 = __builtin_amdgcn_mfma_f32_32x32x16_bf16(xh, bm, accS1, 0, 0, 0);
            accS1 = __builtin_amdgcn_mfma_f32_32x32x16_bf16(xm, bh, accS1, 0, 0, 0);
            accS1 = __builtin_amdgcn_mfma_f32_32x32x16_bf16(xh, bl, accS1, 0, 0, 0);
            accS1 = __builtin_amdgcn_mfma_f32_32x32x16_bf16(xl, bh, accS1, 0, 0, 0);
            accS1 = __builtin_amdgcn_mfma_f32_32x32x16_bf16(xm, bm, accS1, 0, 0, 0);
        }
    };

    // 4-deep pipeline: loads issued 4 chunks ahead of use (~3 chunk-computes
    // of slack >> 900-cycle HBM latency). Named sets: no runtime indexing.
    load(S0, 0); load(S1, 1); load(S2, 2); load(S3, 3);

#pragma unroll 1
    for (int c = 0; c < NCH; c += 4) {
        compute(S0); if (c + 4 < NCH) load(S0, c + 4);
        compute(S1); if (c + 5 < NCH) load(S1, c + 5);
        compute(S2); if (c + 6 < NCH) load(S2, c + 6);
        compute(S3); if (c + 7 < NCH) load(S3, c + 7);
    }

    // ---- K-quarter reduction into slog ----
    // 32x32 C/D layout (m74/m101): col = lane&31, row = (r&3)+8*(r>>2)+4*(l>>5)
#pragma unroll 1
    for (int q = 0; q < 4; ++q) {
        if (kq == q) {
#pragma unroll
            for (int eb = 0; eb < 2; ++eb) {
                const f32x16& AM = eb ? accM1 : accM0;
                const f32x16& AS = eb ? accS1 : accS0;
                const int col = eb * 32 + lr;
#pragma unroll
                for (int r = 0; r < 16; ++r) {
                    const int row = (r & 3) + 8 * (r >> 2) + 4 * l5;
                    const float val = AM[r] + AS[r];
                    if (q == 0) slog[row * LS + col] = val;
                    else        slog[row * LS + col] += val;
                }
            }
        }
        __syncthreads();
    }

    // ---- coalesced logits write: 32 tokens x 64 experts ----
    {
        const int row = t >> 3;           // 0..31
        const int c8  = (t & 7) * 8;
        const float4 o0 = *(const float4*)&slog[row * LS + c8];
        const float4 o1 = *(const float4*)&slog[row * LS + c8 + 4];
        float* dst = out_logits + (size_t)(tok0 + row) * EE + c8;
        *(float4*)dst       = o0;
        *(float4*)(dst + 4) = o1;
    }

    // ---- top-8 + softmax: one lane per token (harness-proven code) ----
    if (t < MT) {
        float tv[TOPK];
        int   ti[TOPK];
#pragma unroll
        for (int q = 0; q < TOPK; ++q) { tv[q] = -INFINITY; ti[q] = 0; }

        for (int e = 0; e < EE; ++e) {
            const float val = slog[t * LS + e];
            if (val > tv[TOPK - 1]) {
                tv[TOPK - 1] = val;
                ti[TOPK - 1] = e;
#pragma unroll
                for (int q = TOPK - 1; q > 0; --q) {
                    if (tv[q] > tv[q - 1]) {   // strict: lowest-index-first on ties
                        float fv = tv[q]; tv[q] = tv[q - 1]; tv[q - 1] = fv;
                        int   fi = ti[q]; ti[q] = ti[q - 1]; ti[q - 1] = fi;
                    }
                }
            }
        }

        const float m = tv[0];
        float ew[TOPK];
        float sum = 0.f;
#pragma unroll
        for (int q = 0; q < TOPK; ++q) { ew[q] = expf(tv[q] - m); sum += ew[q]; }
        const float inv = 1.f / sum;

        const size_t tok = (size_t)(tok0 + t);
        float4 w0, w1, i0, i1;
        w0.x = ew[0] * inv; w0.y = ew[1] * inv; w0.z = ew[2] * inv; w0.w = ew[3] * inv;
        w1.x = ew[4] * inv; w1.y = ew[5] * inv; w1.z = ew[6] * inv; w1.w = ew[7] * inv;
        i0.x = (float)ti[0]; i0.y = (float)ti[1]; i0.z = (float)ti[2]; i0.w = (float)ti[3];
        i1.x = (float)ti[4]; i1.y = (float)ti[5]; i1.z = (float)ti[6]; i1.w = (float)ti[7];
        *(float4*)(out_wts + tok * TOPK)     = w0;
        *(float4*)(out_wts + tok * TOPK + 4) = w1;
        *(float4*)(out_idx + tok * TOPK)     = i0;
        *(float4*)(out_idx + tok * TOPK + 4) = i1;
    }
}

extern "C" void kernel_launch(void* const* d_in, const int* in_sizes, int n_in,
                              void* d_out, int out_size, void* d_ws, size_t ws_size,
                              hipStream_t stream) {
    const float* x = (const float*)d_in[0];   // hidden_states [4,4096,2048] fp32
    const float* w = (const float*)d_in[1];   // gate_w [64,2048] fp32
    float* out        = (float*)d_out;
    float* out_logits = out;                               // 16384*64
    float* out_wts    = out + (size_t)NT * EE;             // 16384*8
    float* out_idx    = out_wts + (size_t)NT * TOPK;       // 16384*8

    hipLaunchKernelGGL(router_fused, dim3(NT / MT), dim3(256), 0, stream,
                       x, w, out_logits, out_wts, out_idx);
}